// Round 4
// baseline (247.472 us; speedup 1.0000x reference)
//
#include <hip/hip_runtime.h>

#define B_TOTAL 32768
#define NF 200
#define D_IN 5
#define NH 15
#define NOUT 30
#define RECS 216          // per-f record: [bc 30][w3 30][Wc 150 (i-major)][pad 6] -> 864 B, 16B aligned

typedef float v2f __attribute__((ext_vector_type(2)));
typedef float v4f __attribute__((ext_vector_type(4)));

// ---------------- Precompute: fold W1*W2, b1*W2+b2, copy w3 into aligned per-f records ----------------
__global__ __launch_bounds__(256) void precompute_kernel(
    const float* __restrict__ W1, const float* __restrict__ b1,
    const float* __restrict__ W2, const float* __restrict__ b2,
    const float* __restrict__ W3, float* __restrict__ rec)
{
    const int f = blockIdx.x;
    const int t = threadIdx.x;
    float* r = rec + f * RECS;
    if (t < NOUT) {
        const int o = t;
        float s = b2[f * NOUT + o];
        #pragma unroll
        for (int h = 0; h < NH; ++h)
            s = fmaf(b1[f * NH + h], W2[(f * NH + h) * NOUT + o], s);
        r[o] = s;                                  // bc
    } else if (t < 2 * NOUT) {
        const int o = t - NOUT;
        r[NOUT + o] = W3[f * NOUT + o];            // w3 copy
    } else if (t < 2 * NOUT + D_IN * NOUT) {
        const int j = t - 2 * NOUT;
        const int i = j / NOUT;
        const int o = j - i * NOUT;
        float s = 0.f;
        #pragma unroll
        for (int h = 0; h < NH; ++h)
            s = fmaf(W1[(f * D_IN + i) * NH + h], W2[(f * NH + h) * NOUT + o], s);
        r[2 * NOUT + i * NOUT + o] = s;            // Wc, i-major, o contiguous (pair-friendly)
    }
}

// ---------------- Main fused kernel ----------------
// lane = batch row; y via direct global float4 (all loads issued up front, one vmcnt wait);
// weights wave-uniform via s_load (SGPR broadcast, replication-1).
// f split 5 ways across blockIdx.y -> 25600 waves total (~8/SIMD steady) to hide
// scalar-load and y-load latency with TLP. Partials combined via fp32 atomicAdd.
#define BTILE 64          // batch rows per block (one per lane)
#define NSUB 10           // waves per block
#define FSUB 4            // f's per wave: 4 f * 5 = 20 floats = 5 float4, 16B-aligned
#define FPARTS 5          // f parts across blockIdx.y (5 * 10 * 4 = 200)

__global__ __launch_bounds__(640, 8) void mlp_kernel(
    const float* __restrict__ y, const float* __restrict__ rec,
    const float* __restrict__ b3, float* __restrict__ out)
{
    __shared__ float red[BTILE * NSUB];

    const int tid   = threadIdx.x;
    const int lane  = tid & 63;
    const int sub   = tid >> 6;                             // 0..9
    const int sub_u = __builtin_amdgcn_readfirstlane(sub);  // provably wave-uniform
    const int b0    = blockIdx.x * BTILE;
    const int b     = b0 + lane;
    const int fp    = blockIdx.y;                           // 0..4
    const int fbase = fp * (NSUB * FSUB) + sub_u * FSUB;    // wave's first f

    const v4f* __restrict__ yq =
        (const v4f*)(y + (size_t)b * (NF * D_IN) + fbase * D_IN);
    const float* __restrict__ wrec = rec + (size_t)fbase * RECS;  // uniform

    // all of this wave's y, issued up front (5 dwordx4 in flight)
    v4f yv[5];
    #pragma unroll
    for (int j = 0; j < 5; ++j) yv[j] = yq[j];

    v2f acc0 = (v2f)0.0f, acc1 = (v2f)0.0f;

    #pragma unroll
    for (int k = 0; k < FSUB; ++k) {
        const float* __restrict__ r  = wrec + k * RECS;             // uniform
        const v2f* __restrict__ rb   = (const v2f*)r;               // bc  pairs
        const v2f* __restrict__ rw3  = (const v2f*)(r + NOUT);      // w3  pairs
        const v2f* __restrict__ rw   = (const v2f*)(r + 2 * NOUT);  // Wc  pairs, rw[i*15+p]

        v2f z[15];
        {   // i = 0 folded with bc init
            const int e = k * 5;
            const float y0 = yv[e >> 2][e & 3];
            #pragma unroll
            for (int p = 0; p < 15; ++p) z[p] = rb[p] + y0 * rw[p];
        }
        #pragma unroll
        for (int i = 1; i < D_IN; ++i) {
            const int e = k * 5 + i;
            const float yi = yv[e >> 2][e & 3];
            #pragma unroll
            for (int p = 0; p < 15; ++p) z[p] += yi * rw[i * 15 + p];
        }
        #pragma unroll
        for (int p = 0; p < 15; ++p) {
            v2f zr = __builtin_elementwise_max(z[p], (v2f)0.0f);    // v_pk_max_f32
            if (p & 1) acc1 += zr * rw3[p];
            else       acc0 += zr * rw3[p];
        }
    }

    v2f accs = acc0 + acc1;
    red[lane * NSUB + sub] = accs.x + accs.y;
    __syncthreads();

    if (tid < BTILE) {
        float s = 0.f;
        #pragma unroll
        for (int k = 0; k < NSUB; ++k) s += red[tid * NSUB + k];
        if (fp == 0) s += b3[0];
        atomicAdd(&out[b0 + tid], s);
    }
}

extern "C" void kernel_launch(void* const* d_in, const int* in_sizes, int n_in,
                              void* d_out, int out_size, void* d_ws, size_t ws_size,
                              hipStream_t stream) {
    const float* y  = (const float*)d_in[0];
    const float* W1 = (const float*)d_in[1];
    const float* b1 = (const float*)d_in[2];
    const float* W2 = (const float*)d_in[3];
    const float* b2 = (const float*)d_in[4];
    const float* W3 = (const float*)d_in[5];
    const float* b3 = (const float*)d_in[6];
    float* out = (float*)d_out;

    float* rec = (float*)d_ws;   // 200 * 216 floats = 172.8 KB of ws

    hipMemsetAsync(out, 0, (size_t)B_TOTAL * sizeof(float), stream);  // atomics accumulate into zeros
    precompute_kernel<<<NF, 256, 0, stream>>>(W1, b1, W2, b2, W3, rec);
    mlp_kernel<<<dim3(B_TOTAL / BTILE, FPARTS), BTILE * NSUB, 0, stream>>>(y, rec, b3, out);
}